// Round 20
// baseline (105.959 us; speedup 1.0000x reference)
//
#include <hip/hip_runtime.h>

#define V_N 4096
#define C_N 32
#define T_N 512
#define VCH 256   // number of v-chunks (16 v each)

typedef float f32x4 __attribute__((ext_vector_type(4)));
typedef __bf16 bf16x4 __attribute__((ext_vector_type(4)));
typedef __bf16 bf16x8 __attribute__((ext_vector_type(8)));

__device__ inline f32x4 fma4(f32x4 a, float b, f32x4 c) {
    f32x4 r;
    r.x = fmaf(a.x, b, c.x); r.y = fmaf(a.y, b, c.y);
    r.z = fmaf(a.z, b, c.z); r.w = fmaf(a.w, b, c.w);
    return r;
}

// ---------------------------------------------------------------------------
// Streaming x-pass, t-QUARTER blocks for 4 blocks/CU TLP (prev: 2 blocks/CU
// grid-limited; all pipes <5% busy -> barrier/latency-bound, more resident
// blocks hide it). Block (vc, q) = 16 v-planes x 128-t quarter; grid 1024.
// Wave w owns c = w*8..w*8+7 via 2-row loads: lane l -> cs=l>>5, t4=l&31,
// c = w*8 + j*2 + cs (j=0..3). Direct loads (no LDS staging; R16-proven
// shape), accT[4]+gacc[4] ~ 70 VGPR << 128 cap of launch_bounds(256,4).
//   partT[c][vc][t] = sum_{vi} x[v,c,t]*U1[v]
//   partG[c][vc][t] = sum_{vi} rhs[v,t]*U2[c,v],  rhs = sum_c x*U3[c]
__global__ __launch_bounds__(256, 4) void k_rt(const float* __restrict__ x,
                                               const float* __restrict__ U1,
                                               const float* __restrict__ U2,
                                               const float* __restrict__ U3,
                                               float* __restrict__ partT,
                                               float* __restrict__ partG) {
    __shared__ f32x4 lsum[2][8][32];      // 8KB: [buf][w*2+cs][t4]
    __shared__ float u2s[32][16];         // 2KB U2 slice [c][vi]
    __shared__ float u1s[16];
    __shared__ float u3s[32];

    const int vc = blockIdx.x >> 2;       // 0..255, 16 v each
    const int q  = blockIdx.x & 3;        // t-quarter
    const int tid = threadIdx.x;
    const int w = tid >> 6;               // wave 0..3
    const int l = tid & 63;               // lane
    const int cs = l >> 5;                // 0..1 c-sub
    const int t4 = l & 31;                // f32x4 slot within quarter
    const int v0 = vc * 16;
    const int cbase = w * 8 + cs;

    if (tid < 16) u1s[tid] = U1[v0 + tid];
    if (tid < 32) u3s[tid] = U3[tid];
    {
        int c = tid >> 3, e = tid & 7;
        u2s[c][e] = U2[(size_t)c * V_N + v0 + e];
        u2s[c][e + 8] = U2[(size_t)c * V_N + v0 + e + 8];
    }
    __syncthreads();

    float u3loc[4];
#pragma unroll
    for (int j = 0; j < 4; ++j) u3loc[j] = u3s[cbase + j * 2];

    f32x4 accT[4], gacc[4];
#pragma unroll
    for (int j = 0; j < 4; ++j) { accT[j] = (f32x4)0.f; gacc[j] = (f32x4)0.f; }

    const float* xbase = x + (size_t)v0 * (C_N * T_N) + q * 128 + t4 * 4;

#pragma unroll 1
    for (int vi = 0; vi < 16; ++vi) {
        const float* xp = xbase + (size_t)vi * (C_N * T_N);
        const int buf = vi & 1;
        float u1 = u1s[vi];
        f32x4 racc = (f32x4)0.f;
#pragma unroll
        for (int j = 0; j < 4; ++j) {
            f32x4 xv = *(const f32x4*)(xp + (size_t)(cbase + j * 2) * T_N);
            accT[j] = fma4(xv, u1, accT[j]);
            racc = fma4(xv, u3loc[j], racc);
        }
        lsum[buf][w * 2 + cs][t4] = racc;
        __syncthreads();
        f32x4 rhs = ((lsum[buf][0][t4] + lsum[buf][1][t4]) +
                     (lsum[buf][2][t4] + lsum[buf][3][t4])) +
                    ((lsum[buf][4][t4] + lsum[buf][5][t4]) +
                     (lsum[buf][6][t4] + lsum[buf][7][t4]));
#pragma unroll
        for (int j = 0; j < 4; ++j)
            gacc[j] = fma4(rhs, u2s[cbase + j * 2][vi], gacc[j]);
    }

    // [c][vc][t] layout stores
#pragma unroll
    for (int j = 0; j < 4; ++j) {
        size_t off = ((size_t)(cbase + j * 2) * VCH + vc) * T_N + q * 128 + t4 * 4;
        *(f32x4*)&partT[off] = accT[j];
        *(f32x4*)&partG[off] = gacc[j];
    }
}

// ---------------------------------------------------------------------------
// Blocks 0..511: fixed-order reduce of 256 chunk-partials -> tmpT, Gc.
// Partials are [c][vc][t] -> vc-loop stride is T_N*4 = 2KB.
// Blocks 512..1023: Ve hi/lo split, x4 vectorized, MFMA A-fragment order.
__global__ __launch_bounds__(128) void k_redpre(const float* __restrict__ partT,
                                                const float* __restrict__ partG,
                                                float* __restrict__ tmpT,
                                                float* __restrict__ Gc,
                                                const float* __restrict__ Ve,
                                                __bf16* __restrict__ VeHi,
                                                __bf16* __restrict__ VeLo) {
    if (blockIdx.x >= 512) {
        int o = ((blockIdx.x - 512) * 128 + threadIdx.x) * 4;  // 0..262140
        int e0 = o & 7, lp = (o >> 3) & 63, tile = o >> 9;
        int kk = tile & 15, tt = tile >> 4;
        int t = tt * 16 + (lp & 15);
        int k = kk * 32 + (lp >> 4) * 8 + e0;
        f32x4 v = *(const f32x4*)&Ve[(size_t)t * T_N + k];
        bf16x4 h, lo;
#pragma unroll
        for (int j = 0; j < 4; ++j) {
            h[j] = (__bf16)v[j];
            lo[j] = (__bf16)(v[j] - (float)h[j]);
        }
        *(bf16x4*)&VeHi[o] = h;
        *(bf16x4*)&VeLo[o] = lo;
        return;
    }
    __shared__ f32x4 red[16][8];
    int oid = threadIdx.x & 15;               // 0..15 (fast -> contiguous)
    int seg = threadIdx.x >> 4;               // 0..7
    int o = blockIdx.x * 16 + oid;            // 0..8191
    int isG = o >> 12;
    int oo = o & 4095;                        // f32x4 slot in [32][128]
    int c = oo >> 7;
    int tq = oo & 127;                        // t = tq*4
    const float* src = isG ? partG : partT;
    size_t base = (size_t)c * VCH * T_N + tq * 4;
    f32x4 s = (f32x4)0.f;
#pragma unroll 4
    for (int vc = seg * 32; vc < seg * 32 + 32; ++vc)
        s += *(const f32x4*)&src[base + (size_t)vc * T_N];
    red[oid][seg] = s;
    __syncthreads();
    if (seg == 0) {
        f32x4 tot = red[oid][0];
#pragma unroll
        for (int k = 1; k < 8; ++k) tot += red[oid][k];
        float* dst = isG ? Gc : tmpT;
        *(f32x4*)&dst[c * T_N + tq * 4] = tot;
    }
}

// ---------------------------------------------------------------------------
// P[s][r] = sum_c Gc[c][s] * tmpT[c][r]    (K=32 tiny GEMM, fp32)
__global__ __launch_bounds__(256) void k_P2(const float* __restrict__ Gc,
                                            const float* __restrict__ tmpT,
                                            float* __restrict__ P) {
    __shared__ float Gs[32][64];
    __shared__ float Ts[32][64];
    int rbase = blockIdx.x * 64, sbase = blockIdx.y * 64;
    int tid = threadIdx.x;
    int tx = tid & 15, ty = tid >> 4;
    for (int i = tid; i < 2048; i += 256) {
        int cc = i >> 6, j = i & 63;
        Gs[cc][j] = Gc[cc * T_N + sbase + j];
        Ts[cc][j] = tmpT[cc * T_N + rbase + j];
    }
    __syncthreads();
    float acc[4][4] = {};
#pragma unroll
    for (int cc = 0; cc < 32; ++cc) {
        float a[4], b[4];
#pragma unroll
        for (int i = 0; i < 4; ++i) a[i] = Gs[cc][ty * 4 + i];
#pragma unroll
        for (int j = 0; j < 4; ++j) b[j] = Ts[cc][tx * 4 + j];
#pragma unroll
        for (int i = 0; i < 4; ++i)
#pragma unroll
            for (int j = 0; j < 4; ++j) acc[i][j] = fmaf(a[i], b[j], acc[i][j]);
    }
#pragma unroll
    for (int i = 0; i < 4; ++i) {
        f32x4 vv = {acc[i][0], acc[i][1], acc[i][2], acc[i][3]};
        *(f32x4*)&P[(size_t)(sbase + ty * 4 + i) * T_N + rbase + tx * 4] = vv;
    }
}

// ---------------------------------------------------------------------------
// Fused (R18-verified): per block (c, 32-wide r tile), all t (512 blocks):
//   S[s][r] = sigmoid(P[s][r] + be[c][s][r])   (bf16, LDS 32KB, XOR-swizzled)
//   E[t][r] = sum_s (VeHi+VeLo)[t][s] * S[s][r]  via MFMA 16x16x32 bf16
//   out[c][t][r] = softmax_t(E)
// 8 waves = 8 disjoint 64-t strips; acc[4 mi][2 ni] covers both r-halves ->
// zero intra-block Ve-fragment duplication.
__global__ __launch_bounds__(512, 4) void k_fused(const float* __restrict__ P,
                                                  const float* __restrict__ be,
                                                  const __bf16* __restrict__ VeHi,
                                                  const __bf16* __restrict__ VeLo,
                                                  float* __restrict__ out) {
    __shared__ __bf16 S[32][512];   // 32KB: S^T layout [r][s], swizzled
    const int rbase = blockIdx.x * 32;
    const int c = blockIdx.y;
    const int tid = threadIdx.x;
    const size_t cTT = (size_t)c * T_N * T_N;

    // ---- phase 1: sigmoid once per element (f32x4 loads), S^T bf16 swizzled
    {
        int r4 = (tid & 7) * 4;
        int s0 = tid >> 3;          // 0..63
        for (int i = 0; i < 8; ++i) {
            int s = i * 64 + s0;
            size_t off = (size_t)s * T_N + rbase + r4;
            f32x4 pv = *(const f32x4*)&P[off];
            f32x4 bv = *(const f32x4*)&be[cTT + off];
#pragma unroll
            for (int j = 0; j < 4; ++j) {
                float vv = pv[j] + bv[j];
                float sg = 1.0f / (1.0f + __expf(-vv));
                int rl = r4 + j;
                S[rl][s ^ ((rl & 7) << 3)] = (__bf16)sg;
            }
        }
    }
    __syncthreads();

    const int lane = tid & 63;
    const int w = tid >> 6;     // 0..7: 64-t strip index
    const int lhi = lane >> 4;  // 0..3
    const int llo = lane & 15;

    const bf16x8* fragHi = (const bf16x8*)VeHi;
    const bf16x8* fragLo = (const bf16x8*)VeLo;

    f32x4 acc[4][2];
#pragma unroll
    for (int mi = 0; mi < 4; ++mi)
#pragma unroll
        for (int ni = 0; ni < 2; ++ni) acc[mi][ni] = (f32x4)0.f;

    // ---- phase 2: K loop (s), A = packed Ve frags (L2-hot, deduped), B LDS
    for (int k0 = 0; k0 < T_N; k0 += 32) {
        bf16x8 b[2];
        int g = (k0 >> 3) + lhi;
#pragma unroll
        for (int ni = 0; ni < 2; ++ni) {
            int rr = ni * 16 + llo;
            b[ni] = *(const bf16x8*)&S[rr][(g ^ (rr & 7)) << 3];
        }
#pragma unroll
        for (int mi = 0; mi < 4; ++mi) {
            int tile = (w * 4 + mi) * 16 + (k0 >> 5);
            bf16x8 ah = fragHi[tile * 64 + lane];
            bf16x8 al = fragLo[tile * 64 + lane];
#pragma unroll
            for (int ni = 0; ni < 2; ++ni) {
                acc[mi][ni] = __builtin_amdgcn_mfma_f32_16x16x32_bf16(ah, b[ni], acc[mi][ni], 0, 0, 0);
                acc[mi][ni] = __builtin_amdgcn_mfma_f32_16x16x32_bf16(al, b[ni], acc[mi][ni], 0, 0, 0);
            }
        }
    }
    __syncthreads();            // done with S; reuse as reduction buffers

    float* red = (float*)&S[0][0];  // [0..255]=max, [256..511]=sum
    float gmax[2], gsum[2];

    // ---- phase 3a: column max over t (8 wave-partials per column)
#pragma unroll
    for (int ni = 0; ni < 2; ++ni) {
        float m = -3.4e38f;
#pragma unroll
        for (int mi = 0; mi < 4; ++mi)
#pragma unroll
            for (int q = 0; q < 4; ++q) m = fmaxf(m, acc[mi][ni][q]);
        m = fmaxf(m, __shfl_xor(m, 16));
        m = fmaxf(m, __shfl_xor(m, 32));
        if (lane < 16) red[w * 32 + ni * 16 + llo] = m;
    }
    __syncthreads();
#pragma unroll
    for (int ni = 0; ni < 2; ++ni) {
        int col = ni * 16 + llo;
        float m = red[col];
#pragma unroll
        for (int wv = 1; wv < 8; ++wv) m = fmaxf(m, red[wv * 32 + col]);
        gmax[ni] = m;
    }
    // ---- phase 3b: exp + column sum
#pragma unroll
    for (int ni = 0; ni < 2; ++ni) {
        float ssum = 0.f;
#pragma unroll
        for (int mi = 0; mi < 4; ++mi)
#pragma unroll
            for (int q = 0; q < 4; ++q) {
                float e = __expf(acc[mi][ni][q] - gmax[ni]);
                acc[mi][ni][q] = e;
                ssum += e;
            }
        ssum += __shfl_xor(ssum, 16);
        ssum += __shfl_xor(ssum, 32);
        if (lane < 16) red[256 + w * 32 + ni * 16 + llo] = ssum;
    }
    __syncthreads();
#pragma unroll
    for (int ni = 0; ni < 2; ++ni) {
        int col = ni * 16 + llo;
        float s = red[256 + col];
#pragma unroll
        for (int wv = 1; wv < 8; ++wv) s += red[256 + wv * 32 + col];
        gsum[ni] = 1.0f / s;
    }
    // ---- phase 3c: write normalized output
#pragma unroll
    for (int mi = 0; mi < 4; ++mi)
#pragma unroll
        for (int ni = 0; ni < 2; ++ni) {
            int rg = rbase + ni * 16 + llo;
#pragma unroll
            for (int q = 0; q < 4; ++q) {
                int t = w * 64 + mi * 16 + lhi * 4 + q;
                out[cTT + (size_t)t * T_N + rg] = acc[mi][ni][q] * gsum[ni];
            }
        }
}

// ---------------------------------------------------------------------------
extern "C" void kernel_launch(void* const* d_in, const int* in_sizes, int n_in,
                              void* d_out, int out_size, void* d_ws, size_t ws_size,
                              hipStream_t stream) {
    const float* x  = (const float*)d_in[0];
    const float* U1 = (const float*)d_in[1];
    const float* U2 = (const float*)d_in[2];
    const float* U3 = (const float*)d_in[3];
    const float* be = (const float*)d_in[4];
    const float* Ve = (const float*)d_in[5];
    float* out = (float*)d_out;

    float* ws    = (float*)d_ws;
    float* partT = ws;                        // 32*256*512 = 4194304 floats
    float* partG = ws + 4194304;              // 4194304
    float* P     = ws + 8388608;              // 262144
    __bf16* VeHi = (__bf16*)(ws + 8650752);   // 262144 bf16 (131072 slots)
    __bf16* VeLo = (__bf16*)(ws + 8781824);   // 262144 bf16
    float* tmpT  = ws + 8912896;              // 16384
    float* Gc    = ws + 8929280;              // 16384
    // total ~8945664 floats ~= 35.8 MB

    k_rt    <<<1024, 256, 0, stream>>>(x, U1, U2, U3, partT, partG);
    k_redpre<<<512 + 512, 128, 0, stream>>>(partT, partG, tmpT, Gc, Ve, VeHi, VeLo);
    k_P2    <<<dim3(8, 8), 256, 0, stream>>>(Gc, tmpT, P);
    k_fused <<<dim3(16, C_N), 512, 0, stream>>>(P, be, VeHi, VeLo, out);
}

// Round 21
// 104.931 us; speedup vs baseline: 1.0098x; 1.0098x over previous
//
#include <hip/hip_runtime.h>

#define V_N 4096
#define C_N 32
#define T_N 512

typedef float f32x4 __attribute__((ext_vector_type(4)));
typedef __bf16 bf16x4 __attribute__((ext_vector_type(4)));
typedef __bf16 bf16x8 __attribute__((ext_vector_type(8)));

__device__ inline f32x4 fma4(f32x4 a, float b, f32x4 c) {
    f32x4 r;
    r.x = fmaf(a.x, b, c.x); r.y = fmaf(a.y, b, c.y);
    r.z = fmaf(a.z, b, c.z); r.w = fmaf(a.w, b, c.w);
    return r;
}

// ---------------------------------------------------------------------------
// Streaming x-pass with global_load_lds pipeline (R17/R18-verified best).
// Block (vc, half) = 16 v-planes x 256-t half. Wave w stages AND reads only
// rows c = w*8..w*8+7 -> xbuf needs no barrier; only the lsum combine
// barriers (lgkmcnt(0) + raw s_barrier, vmcnt unfenced).
//   partT[vc][c][t] = sum_{vi} x[v,c,t]*U1[v]
//   partG[vc][c][t] = sum_{vi} rhs[v,t]*U2[c,v],  rhs = sum_c x*U3[c]
// NOTE (R19/R20 post-mortems): [c][vc][t] partials transpose and t-quarter
// 4-blocks/CU variants are NEUTRAL; 7 structural variants all land at
// ~73us = ~4.1 TB/s — structural rate limit for this L3/HBM mix. FROZEN.
__global__ __launch_bounds__(256, 1) void k_rt(const float* __restrict__ x,
                                               const float* __restrict__ U1,
                                               const float* __restrict__ U2,
                                               const float* __restrict__ U3,
                                               float* __restrict__ partT,
                                               float* __restrict__ partG) {
    __shared__ float xbuf[2][32][256];    // 64KB double-buffered plane
    __shared__ f32x4 lsum[2][4][64];      // 8KB cross-wave rhs combine
    __shared__ float u2s[32][16];         // 2KB U2 slice [c][vi]
    __shared__ float u1s[16];
    __shared__ float u3s[32];

    const int vc = blockIdx.x >> 1;       // 0..255, 16 v each
    const int half = blockIdx.x & 1;      // t-half
    const int tid = threadIdx.x;
    const int w = tid >> 6;               // wave 0..3
    const int l = tid & 63;               // lane
    const int v0 = vc * 16;

    if (tid < 16) u1s[tid] = U1[v0 + tid];
    if (tid < 32) u3s[tid] = U3[tid];
    {
        int c = tid >> 3, e = tid & 7;
        u2s[c][e] = U2[(size_t)c * V_N + v0 + e];
        u2s[c][e + 8] = U2[(size_t)c * V_N + v0 + e + 8];
    }
    __syncthreads();

    float u3loc[8];
#pragma unroll
    for (int i = 0; i < 8; ++i) u3loc[i] = u3s[w * 8 + i];

    f32x4 accT[8], gacc[8];
#pragma unroll
    for (int i = 0; i < 8; ++i) { accT[i] = (f32x4)0.f; gacc[i] = (f32x4)0.f; }

    const float* xbase = x + (size_t)v0 * (C_N * T_N) + half * 256 + l * 4;

#define STAGE(vi) {                                                          \
    const float* xp_ = xbase + (size_t)(vi) * (C_N * T_N);                   \
    _Pragma("unroll")                                                        \
    for (int i_ = 0; i_ < 8; ++i_) {                                         \
        __builtin_amdgcn_global_load_lds(                                    \
            (const __attribute__((address_space(1))) void*)                  \
                (xp_ + (size_t)(w * 8 + i_) * T_N),                          \
            (__attribute__((address_space(3))) void*)                        \
                &xbuf[(vi) & 1][w * 8 + i_][0],                              \
            16, 0, 0);                                                       \
    } }

    STAGE(0);
#pragma unroll 1
    for (int vi = 0; vi < 16; ++vi) {
        const int buf = vi & 1;
        if (vi + 1 < 16) {
            STAGE(vi + 1);
            asm volatile("s_waitcnt vmcnt(8)" ::: "memory");
        } else {
            asm volatile("s_waitcnt vmcnt(0)" ::: "memory");
        }
        __builtin_amdgcn_sched_barrier(0);
        float u1 = u1s[vi];
        f32x4 racc = (f32x4)0.f;
#pragma unroll
        for (int i = 0; i < 8; ++i) {
            f32x4 xv = *(const f32x4*)&xbuf[buf][w * 8 + i][l * 4];
            accT[i] = fma4(xv, u1, accT[i]);
            racc = fma4(xv, u3loc[i], racc);
        }
        lsum[buf][w][l] = racc;
        asm volatile("s_waitcnt lgkmcnt(0)" ::: "memory");
        __builtin_amdgcn_sched_barrier(0);
        __builtin_amdgcn_s_barrier();                    // raw: vmcnt unfenced
        f32x4 rhs = (lsum[buf][0][l] + lsum[buf][1][l]) +
                    (lsum[buf][2][l] + lsum[buf][3][l]);
#pragma unroll
        for (int i = 0; i < 8; ++i)
            gacc[i] = fma4(rhs, u2s[w * 8 + i][vi], gacc[i]);
    }
#undef STAGE

    const size_t pbase = (size_t)vc * (C_N * T_N) + half * 256 + l * 4;
#pragma unroll
    for (int i = 0; i < 8; ++i) {
        size_t off = pbase + (size_t)(w * 8 + i) * T_N;
        *(f32x4*)&partT[off] = accT[i];
        *(f32x4*)&partG[off] = gacc[i];
    }
}

// ---------------------------------------------------------------------------
// Blocks 0..511: fixed-order reduce of 256 chunk-partials -> tmpT, Gc.
// Blocks 512..1023: Ve hi/lo split, x4 vectorized, MFMA A-fragment order.
__global__ __launch_bounds__(128) void k_redpre(const float* __restrict__ partT,
                                                const float* __restrict__ partG,
                                                float* __restrict__ tmpT,
                                                float* __restrict__ Gc,
                                                const float* __restrict__ Ve,
                                                __bf16* __restrict__ VeHi,
                                                __bf16* __restrict__ VeLo) {
    if (blockIdx.x >= 512) {
        int o = ((blockIdx.x - 512) * 128 + threadIdx.x) * 4;  // 0..262140
        int e0 = o & 7, lp = (o >> 3) & 63, tile = o >> 9;
        int kk = tile & 15, tt = tile >> 4;
        int t = tt * 16 + (lp & 15);
        int k = kk * 32 + (lp >> 4) * 8 + e0;
        f32x4 v = *(const f32x4*)&Ve[(size_t)t * T_N + k];
        bf16x4 h, lo;
#pragma unroll
        for (int j = 0; j < 4; ++j) {
            h[j] = (__bf16)v[j];
            lo[j] = (__bf16)(v[j] - (float)h[j]);
        }
        *(bf16x4*)&VeHi[o] = h;
        *(bf16x4*)&VeLo[o] = lo;
        return;
    }
    __shared__ f32x4 red[16][8];
    int oid = threadIdx.x & 15;               // 0..15 (fast -> contiguous)
    int seg = threadIdx.x >> 4;               // 0..7
    int o = blockIdx.x * 16 + oid;            // 0..8191
    int isG = o >> 12;
    int oo = o & 4095;                        // f32x4 slot in [32][128]
    int c = oo >> 7;
    int tq = oo & 127;                        // t = tq*4
    const float* src = isG ? partG : partT;
    size_t base = (size_t)c * T_N + tq * 4;
    f32x4 s = (f32x4)0.f;
#pragma unroll 4
    for (int vc = seg * 32; vc < seg * 32 + 32; ++vc)
        s += *(const f32x4*)&src[base + (size_t)vc * (C_N * T_N)];
    red[oid][seg] = s;
    __syncthreads();
    if (seg == 0) {
        f32x4 tot = red[oid][0];
#pragma unroll
        for (int k = 1; k < 8; ++k) tot += red[oid][k];
        float* dst = isG ? Gc : tmpT;
        *(f32x4*)&dst[c * T_N + tq * 4] = tot;
    }
}

// ---------------------------------------------------------------------------
// P[s][r] = sum_c Gc[c][s] * tmpT[c][r]    (K=32 tiny GEMM, fp32)
__global__ __launch_bounds__(256) void k_P2(const float* __restrict__ Gc,
                                            const float* __restrict__ tmpT,
                                            float* __restrict__ P) {
    __shared__ float Gs[32][64];
    __shared__ float Ts[32][64];
    int rbase = blockIdx.x * 64, sbase = blockIdx.y * 64;
    int tid = threadIdx.x;
    int tx = tid & 15, ty = tid >> 4;
    for (int i = tid; i < 2048; i += 256) {
        int cc = i >> 6, j = i & 63;
        Gs[cc][j] = Gc[cc * T_N + sbase + j];
        Ts[cc][j] = tmpT[cc * T_N + rbase + j];
    }
    __syncthreads();
    float acc[4][4] = {};
#pragma unroll
    for (int cc = 0; cc < 32; ++cc) {
        float a[4], b[4];
#pragma unroll
        for (int i = 0; i < 4; ++i) a[i] = Gs[cc][ty * 4 + i];
#pragma unroll
        for (int j = 0; j < 4; ++j) b[j] = Ts[cc][tx * 4 + j];
#pragma unroll
        for (int i = 0; i < 4; ++i)
#pragma unroll
            for (int j = 0; j < 4; ++j) acc[i][j] = fmaf(a[i], b[j], acc[i][j]);
    }
#pragma unroll
    for (int i = 0; i < 4; ++i) {
        f32x4 vv = {acc[i][0], acc[i][1], acc[i][2], acc[i][3]};
        *(f32x4*)&P[(size_t)(sbase + ty * 4 + i) * T_N + rbase + tx * 4] = vv;
    }
}

// ---------------------------------------------------------------------------
// Fused (R18-verified): per block (c, 32-wide r tile), all t (512 blocks):
//   S[s][r] = sigmoid(P[s][r] + be[c][s][r])   (bf16, LDS 32KB, XOR-swizzled)
//   E[t][r] = sum_s (VeHi+VeLo)[t][s] * S[s][r]  via MFMA 16x16x32 bf16
//   out[c][t][r] = softmax_t(E)
// 8 waves = 8 disjoint 64-t strips; acc[4 mi][2 ni] covers both r-halves ->
// zero intra-block Ve-fragment duplication.
__global__ __launch_bounds__(512, 4) void k_fused(const float* __restrict__ P,
                                                  const float* __restrict__ be,
                                                  const __bf16* __restrict__ VeHi,
                                                  const __bf16* __restrict__ VeLo,
                                                  float* __restrict__ out) {
    __shared__ __bf16 S[32][512];   // 32KB: S^T layout [r][s], swizzled
    const int rbase = blockIdx.x * 32;
    const int c = blockIdx.y;
    const int tid = threadIdx.x;
    const size_t cTT = (size_t)c * T_N * T_N;

    // ---- phase 1: sigmoid once per element (f32x4 loads), S^T bf16 swizzled
    {
        int r4 = (tid & 7) * 4;
        int s0 = tid >> 3;          // 0..63
        for (int i = 0; i < 8; ++i) {
            int s = i * 64 + s0;
            size_t off = (size_t)s * T_N + rbase + r4;
            f32x4 pv = *(const f32x4*)&P[off];
            f32x4 bv = *(const f32x4*)&be[cTT + off];
#pragma unroll
            for (int j = 0; j < 4; ++j) {
                float vv = pv[j] + bv[j];
                float sg = 1.0f / (1.0f + __expf(-vv));
                int rl = r4 + j;
                S[rl][s ^ ((rl & 7) << 3)] = (__bf16)sg;
            }
        }
    }
    __syncthreads();

    const int lane = tid & 63;
    const int w = tid >> 6;     // 0..7: 64-t strip index
    const int lhi = lane >> 4;  // 0..3
    const int llo = lane & 15;

    const bf16x8* fragHi = (const bf16x8*)VeHi;
    const bf16x8* fragLo = (const bf16x8*)VeLo;

    f32x4 acc[4][2];
#pragma unroll
    for (int mi = 0; mi < 4; ++mi)
#pragma unroll
        for (int ni = 0; ni < 2; ++ni) acc[mi][ni] = (f32x4)0.f;

    // ---- phase 2: K loop (s), A = packed Ve frags (L2-hot, deduped), B LDS
    for (int k0 = 0; k0 < T_N; k0 += 32) {
        bf16x8 b[2];
        int g = (k0 >> 3) + lhi;
#pragma unroll
        for (int ni = 0; ni < 2; ++ni) {
            int rr = ni * 16 + llo;
            b[ni] = *(const bf16x8*)&S[rr][(g ^ (rr & 7)) << 3];
        }
#pragma unroll
        for (int mi = 0; mi < 4; ++mi) {
            int tile = (w * 4 + mi) * 16 + (k0 >> 5);
            bf16x8 ah = fragHi[tile * 64 + lane];
            bf16x8 al = fragLo[tile * 64 + lane];
#pragma unroll
            for (int ni = 0; ni < 2; ++ni) {
                acc[mi][ni] = __builtin_amdgcn_mfma_f32_16x16x32_bf16(ah, b[ni], acc[mi][ni], 0, 0, 0);
                acc[mi][ni] = __builtin_amdgcn_mfma_f32_16x16x32_bf16(al, b[ni], acc[mi][ni], 0, 0, 0);
            }
        }
    }
    __syncthreads();            // done with S; reuse as reduction buffers

    float* red = (float*)&S[0][0];  // [0..255]=max, [256..511]=sum
    float gmax[2], gsum[2];

    // ---- phase 3a: column max over t (8 wave-partials per column)
#pragma unroll
    for (int ni = 0; ni < 2; ++ni) {
        float m = -3.4e38f;
#pragma unroll
        for (int mi = 0; mi < 4; ++mi)
#pragma unroll
            for (int q = 0; q < 4; ++q) m = fmaxf(m, acc[mi][ni][q]);
        m = fmaxf(m, __shfl_xor(m, 16));
        m = fmaxf(m, __shfl_xor(m, 32));
        if (lane < 16) red[w * 32 + ni * 16 + llo] = m;
    }
    __syncthreads();
#pragma unroll
    for (int ni = 0; ni < 2; ++ni) {
        int col = ni * 16 + llo;
        float m = red[col];
#pragma unroll
        for (int wv = 1; wv < 8; ++wv) m = fmaxf(m, red[wv * 32 + col]);
        gmax[ni] = m;
    }
    // ---- phase 3b: exp + column sum
#pragma unroll
    for (int ni = 0; ni < 2; ++ni) {
        float ssum = 0.f;
#pragma unroll
        for (int mi = 0; mi < 4; ++mi)
#pragma unroll
            for (int q = 0; q < 4; ++q) {
                float e = __expf(acc[mi][ni][q] - gmax[ni]);
                acc[mi][ni][q] = e;
                ssum += e;
            }
        ssum += __shfl_xor(ssum, 16);
        ssum += __shfl_xor(ssum, 32);
        if (lane < 16) red[256 + w * 32 + ni * 16 + llo] = ssum;
    }
    __syncthreads();
#pragma unroll
    for (int ni = 0; ni < 2; ++ni) {
        int col = ni * 16 + llo;
        float s = red[256 + col];
#pragma unroll
        for (int wv = 1; wv < 8; ++wv) s += red[256 + wv * 32 + col];
        gsum[ni] = 1.0f / s;
    }
    // ---- phase 3c: write normalized output
#pragma unroll
    for (int mi = 0; mi < 4; ++mi)
#pragma unroll
        for (int ni = 0; ni < 2; ++ni) {
            int rg = rbase + ni * 16 + llo;
#pragma unroll
            for (int q = 0; q < 4; ++q) {
                int t = w * 64 + mi * 16 + lhi * 4 + q;
                out[cTT + (size_t)t * T_N + rg] = acc[mi][ni][q] * gsum[ni];
            }
        }
}

// ---------------------------------------------------------------------------
extern "C" void kernel_launch(void* const* d_in, const int* in_sizes, int n_in,
                              void* d_out, int out_size, void* d_ws, size_t ws_size,
                              hipStream_t stream) {
    const float* x  = (const float*)d_in[0];
    const float* U1 = (const float*)d_in[1];
    const float* U2 = (const float*)d_in[2];
    const float* U3 = (const float*)d_in[3];
    const float* be = (const float*)d_in[4];
    const float* Ve = (const float*)d_in[5];
    float* out = (float*)d_out;

    float* ws    = (float*)d_ws;
    float* partT = ws;                        // 256*32*512 = 4194304 floats
    float* partG = ws + 4194304;              // 4194304
    float* P     = ws + 8388608;              // 262144
    __bf16* VeHi = (__bf16*)(ws + 8650752);   // 262144 bf16 (131072 slots)
    __bf16* VeLo = (__bf16*)(ws + 8781824);   // 262144 bf16
    float* tmpT  = ws + 8912896;              // 16384
    float* Gc    = ws + 8929280;              // 16384
    // total ~8945664 floats ~= 35.8 MB

    k_rt    <<<512, 256, 0, stream>>>(x, U1, U2, U3, partT, partG);
    k_redpre<<<512 + 512, 128, 0, stream>>>(partT, partG, tmpT, Gc, Ve, VeHi, VeLo);
    k_P2    <<<dim3(8, 8), 256, 0, stream>>>(Gc, tmpT, P);
    k_fused <<<dim3(16, C_N), 512, 0, stream>>>(P, be, VeHi, VeLo, out);
}